// Round 3
// baseline (79.122 us; speedup 1.0000x reference)
//
#include <hip/hip_runtime.h>
#include <stdint.h>

typedef uint32_t u32;
typedef unsigned short u16;

#define LDT 40  // padded LDS row stride (elements) -> 80B rows, 16B-aligned, 2-way bank alias (free)

typedef __bf16 bf16x8 __attribute__((ext_vector_type(8)));
typedef float  f32x4  __attribute__((ext_vector_type(4)));

__device__ __forceinline__ float bf2f(u16 x) {
  union { float f; u32 u; } c; c.u = ((u32)x) << 16; return c.f;
}
__device__ __forceinline__ u16 f2bf(float f) {
  union { float f; u32 u; } c; c.f = f;
  u32 b = c.u;
  return (u16)((b + 0x7FFFu + ((b >> 16) & 1u)) >> 16);
}
__device__ __forceinline__ u32 pk2(float lo, float hi) {
  return (u32)f2bf(lo) | ((u32)f2bf(hi) << 16);
}

// ---------------------------------------------------------------------------
// Kernel 0: transpose+cast Wq/Wk/Wv (f32 [256][256] -> bf16 WT [n][k])
// ---------------------------------------------------------------------------
__global__ __launch_bounds__(256) void prep_transpose(
    const float* __restrict__ Wq, const float* __restrict__ Wk, const float* __restrict__ Wv,
    u16* __restrict__ WTq, u16* __restrict__ WTk, u16* __restrict__ WTv)
{
  int z = blockIdx.z, bx = blockIdx.x, by = blockIdx.y;
  int x = threadIdx.x, y = threadIdx.y;  // 32 x 8
  __shared__ u16 tile[32][33];
  const float* W  = (z == 0) ? Wq : (z == 1) ? Wk : Wv;
  u16*         WT = (z == 0) ? WTq : (z == 1) ? WTk : WTv;
  for (int yy = y; yy < 32; yy += 8)
    tile[yy][x] = f2bf(W[(size_t)(by * 32 + yy) * 256 + bx * 32 + x]);
  __syncthreads();
  for (int yy = y; yy < 32; yy += 8)
    WT[(size_t)(bx * 32 + yy) * 256 + by * 32 + x] = tile[x][yy];
}

// ---------------------------------------------------------------------------
// Kernel 0b: combined weights CT[z][c][k] = (W{q,k} @ Wg1)^T  (bf16, c<24),
//            bcomb[z][c] = b{q,k}@Wg1 (+ -bg1 for z=0)
// grid (24, 2), 256 threads (= k_in)
// ---------------------------------------------------------------------------
__global__ __launch_bounds__(256) void prep_comb(
    const u16* __restrict__ WTq, const u16* __restrict__ WTk,
    const float* __restrict__ Wg1, const float* __restrict__ bg1,
    const float* __restrict__ bq, const float* __restrict__ bk,
    u16* __restrict__ CT, float* __restrict__ bcomb)
{
  int c = blockIdx.x, z = blockIdx.y;
  int t = threadIdx.x;
  const u16*   WT = (z == 0) ? WTq : WTk;
  const float* b  = (z == 0) ? bq : bk;

  float acc = 0.f;
#pragma unroll 8
  for (int e = 0; e < 256; e++)
    acc += bf2f(WT[(size_t)e * 256 + t]) * Wg1[(size_t)e * 24 + c];
  CT[(size_t)z * 8192 + (size_t)c * 256 + t] = f2bf(acc);

  __shared__ float red[256];
  red[t] = b[t] * Wg1[(size_t)t * 24 + c];
  __syncthreads();
  for (int s = 128; s > 0; s >>= 1) {
    if (t < s) red[t] += red[t + s];
    __syncthreads();
  }
  if (t == 0)
    bcomb[z * 24 + c] = red[0] - ((z == 0) ? bg1[c] : 0.f);
}

// ---------------------------------------------------------------------------
// Kernel 1: projections. blockIdx.x<2: Y[8192,256]=X@W+b (bf16 out).
// blockIdx.x==2: extra 24 cols via combined weights -> qadj/kg1 (f32 out).
// ---------------------------------------------------------------------------
__global__ __launch_bounds__(256) void gemm_qkv(
    const float* __restrict__ Xq, const float* __restrict__ Xk, const float* __restrict__ Xv,
    const u16* __restrict__ WTq, const u16* __restrict__ WTk, const u16* __restrict__ WTv,
    const float* __restrict__ bq, const float* __restrict__ bk, const float* __restrict__ bv,
    const u16* __restrict__ CT, const float* __restrict__ bcomb,
    u16* __restrict__ Oq, u16* __restrict__ Ok, u16* __restrict__ Ov,
    float* __restrict__ qadj, float* __restrict__ kg1)
{
  int z = blockIdx.z;
  int nblk = blockIdx.x;
  if (nblk == 2 && z == 2) return;

  const float* X = (z == 0) ? Xq : (z == 1) ? Xk : Xv;
  int m0 = blockIdx.y * 128;
  int t = threadIdx.x;
  int lane = t & 63, wid = t >> 6;
  int fr = lane & 15, fg = lane >> 4;
  int sr = t >> 1;         // row within 128-row tile
  int sc = (t & 1) * 16;   // 16-element k chunk

  __shared__ __align__(16) u16 la[128 * LDT];
  __shared__ __align__(16) u16 lb[128 * LDT];

  if (nblk < 2) {
    const u16*   WT   = (z == 0) ? WTq : (z == 1) ? WTk : WTv;
    const float* bias = (z == 0) ? bq : (z == 1) ? bk : bv;
    u16*         O    = (z == 0) ? Oq : (z == 1) ? Ok : Ov;
    int n0 = nblk * 128;
    int wr = wid >> 1, wc = wid & 1;

    f32x4 acc[4][4];
#pragma unroll
    for (int i = 0; i < 4; i++)
#pragma unroll
      for (int j = 0; j < 4; j++) acc[i][j] = (f32x4){0.f, 0.f, 0.f, 0.f};

    for (int kt = 0; kt < 256; kt += 32) {
      const float4* ga = (const float4*)(X + (size_t)(m0 + sr) * 256 + kt + sc);
      float4 a0 = ga[0], a1 = ga[1], a2 = ga[2], a3 = ga[3];
      const uint4* gb = (const uint4*)(WT + (size_t)(n0 + sr) * 256 + kt + sc);
      uint4 b0 = gb[0], b1 = gb[1];

      uint4 wa0, wa1;
      wa0.x = pk2(a0.x, a0.y); wa0.y = pk2(a0.z, a0.w);
      wa0.z = pk2(a1.x, a1.y); wa0.w = pk2(a1.z, a1.w);
      wa1.x = pk2(a2.x, a2.y); wa1.y = pk2(a2.z, a2.w);
      wa1.z = pk2(a3.x, a3.y); wa1.w = pk2(a3.z, a3.w);

      __syncthreads();
      *(uint4*)&la[sr * LDT + sc]     = wa0;
      *(uint4*)&la[sr * LDT + sc + 8] = wa1;
      *(uint4*)&lb[sr * LDT + sc]     = b0;
      *(uint4*)&lb[sr * LDT + sc + 8] = b1;
      __syncthreads();

      bf16x8 af[4], bfr[4];
#pragma unroll
      for (int s = 0; s < 4; s++)
        af[s] = *(const bf16x8*)&la[(wr * 64 + s * 16 + fr) * LDT + fg * 8];
#pragma unroll
      for (int s = 0; s < 4; s++)
        bfr[s] = *(const bf16x8*)&lb[(wc * 64 + s * 16 + fr) * LDT + fg * 8];
#pragma unroll
      for (int i = 0; i < 4; i++)
#pragma unroll
        for (int j = 0; j < 4; j++)
          acc[i][j] = __builtin_amdgcn_mfma_f32_16x16x32_bf16(af[i], bfr[j], acc[i][j], 0, 0, 0);
    }

#pragma unroll
    for (int i = 0; i < 4; i++) {
      int rowb = m0 + wr * 64 + i * 16 + fg * 4;
#pragma unroll
      for (int j = 0; j < 4; j++) {
        int col = n0 + wc * 64 + j * 16 + fr;
        float bb = bias[col];
#pragma unroll
        for (int r = 0; r < 4; r++)
          O[(size_t)(rowb + r) * 256 + col] = f2bf(acc[i][j][r] + bb);
      }
    }
  } else {
    // extra 24 cols: O = X @ CT[z]^T + bcomb[z]
    const u16*   BT = CT + (size_t)z * 8192;   // [32][256]
    const float* bc = bcomb + z * 24;
    float*       O  = (z == 0) ? qadj : kg1;

    f32x4 acc[2][2];
#pragma unroll
    for (int i = 0; i < 2; i++)
#pragma unroll
      for (int j = 0; j < 2; j++) acc[i][j] = (f32x4){0.f, 0.f, 0.f, 0.f};

    for (int kt = 0; kt < 256; kt += 32) {
      const float4* ga = (const float4*)(X + (size_t)(m0 + sr) * 256 + kt + sc);
      float4 a0 = ga[0], a1 = ga[1], a2 = ga[2], a3 = ga[3];
      uint4 b0, b1;
      if (t < 64) {
        const uint4* gb = (const uint4*)(BT + (size_t)sr * 256 + kt + sc);
        b0 = gb[0]; b1 = gb[1];
      }
      uint4 wa0, wa1;
      wa0.x = pk2(a0.x, a0.y); wa0.y = pk2(a0.z, a0.w);
      wa0.z = pk2(a1.x, a1.y); wa0.w = pk2(a1.z, a1.w);
      wa1.x = pk2(a2.x, a2.y); wa1.y = pk2(a2.z, a2.w);
      wa1.z = pk2(a3.x, a3.y); wa1.w = pk2(a3.z, a3.w);

      __syncthreads();
      *(uint4*)&la[sr * LDT + sc]     = wa0;
      *(uint4*)&la[sr * LDT + sc + 8] = wa1;
      if (t < 64) {
        *(uint4*)&lb[sr * LDT + sc]     = b0;
        *(uint4*)&lb[sr * LDT + sc + 8] = b1;
      }
      __syncthreads();

      bf16x8 af[2], bfr[2];
#pragma unroll
      for (int s = 0; s < 2; s++)
        af[s] = *(const bf16x8*)&la[(wid * 32 + s * 16 + fr) * LDT + fg * 8];
#pragma unroll
      for (int s = 0; s < 2; s++)
        bfr[s] = *(const bf16x8*)&lb[(s * 16 + fr) * LDT + fg * 8];
#pragma unroll
      for (int i = 0; i < 2; i++)
#pragma unroll
        for (int j = 0; j < 2; j++)
          acc[i][j] = __builtin_amdgcn_mfma_f32_16x16x32_bf16(af[i], bfr[j], acc[i][j], 0, 0, 0);
    }

#pragma unroll
    for (int i = 0; i < 2; i++) {
      int rowb = m0 + wid * 32 + i * 16 + fg * 4;
#pragma unroll
      for (int j = 0; j < 2; j++) {
        int col = j * 16 + fr;
        if (col < 24) {
#pragma unroll
          for (int r = 0; r < 4; r++)
            O[(size_t)(rowb + r) * 24 + col] = acc[i][j][r] + bc[col];
        }
      }
    }
  }
}

// ---------------------------------------------------------------------------
// Kernel 2: logits + softmax -> att[P][8][32] f32. One block per point.
// Touches only kbuf (gather) -> 4MB working set, L2-resident.
// ---------------------------------------------------------------------------
__global__ __launch_bounds__(256) void attn_logits(
    const u16* __restrict__ qb, const u16* __restrict__ kb,
    const float* __restrict__ kg1, const float* __restrict__ qadj,
    const int* __restrict__ ip, const float* __restrict__ raw,
    const float* __restrict__ rpe, const float* __restrict__ wg2b,
    const float* __restrict__ bg2b, float* __restrict__ att)
{
  int p = blockIdx.x, t = threadIdx.x;
  __shared__ __align__(16) float q_s[256];
  __shared__            int   idx_s[32];
  __shared__            float rpe_s[96];
  __shared__            float sh_s[32][3];
  __shared__            float qadj_s[24];
  __shared__            float bg2_s[24];
  __shared__            float wg2_s[576];
  __shared__ __align__(16) float kg1_s[32 * 24];
  __shared__            float pre_s[32][24];
  __shared__            float logit_s[32][8];
  __shared__            float ps_s[64];
  __shared__            float is_s[8];

  q_s[t] = bf2f(qb[(size_t)p * 256 + t]);
  if (t < 96) rpe_s[t] = rpe[(size_t)p * 96 + t];
  if (t < 32) idx_s[t] = ip[(size_t)p * 32 + t];
  if (t >= 128 && t < 152) qadj_s[t - 128] = qadj[(size_t)p * 24 + (t - 128)];
  if (t >= 160 && t < 184) bg2_s[t - 160] = bg2b[t - 160];
  if (t < 192) {
    wg2_s[t]       = wg2b[t];
    wg2_s[t + 192] = wg2b[t + 192];
    wg2_s[t + 384] = wg2b[t + 384];
  }
  __syncthreads();

  if (t < 32) {
    float x  = rpe_s[t * 3 + 0];
    float y  = rpe_s[t * 3 + 1];
    float zz = rpe_s[t * 3 + 2];
    float rl = sqrtf(x * x + y * y + zz * zz);
    float inv = 1.f / fmaxf(rl, 1e-12f);
    float tt = (rl - 0.001f) * 250.f;
    tt = fminf(fmaxf(tt, 0.f), 1.f);
    float cut = 0.5f * (1.f - cosf(tt * 3.14159265358979f));
    float s3c = 1.7320508075688772f * inv * cut;
    sh_s[t][0] = x * s3c; sh_s[t][1] = y * s3c; sh_s[t][2] = zz * s3c;
  }
  if (t < 192) {  // gathered kg1 rows: 32 rows x 6 float4
    int n = t / 6, f = t % 6;
    const float4* kp = (const float4*)(kg1 + (size_t)idx_s[n] * 24);
    *(float4*)&kg1_s[n * 24 + f * 4] = kp[f];
  }
  __syncthreads();

  {  // pre-activation + relu
    int n = t >> 3, jj = t & 7;
#pragma unroll
    for (int c = 0; c < 3; c++) {
      int i = jj * 3 + c;
      pre_s[n][i] = fmaxf(kg1_s[n * 24 + i] - qadj_s[i], 0.f);
    }
  }
  __syncthreads();

  {  // logits + exp (no max-sub: |logit| bounded ~8, f32-safe): thread = (n, h)
    int n = t >> 3, h = t & 7;
    const uint4*  kr = (const uint4*)(kb + (size_t)idx_s[n] * 256 + h * 32);
    const float4* qr = (const float4*)(q_s + h * 32);
    float dot = 0.f;
#pragma unroll
    for (int c = 0; c < 4; c++) {
      uint4 kw = kr[c];
      float4 q0 = qr[2 * c], q1 = qr[2 * c + 1];
      dot += bf2f((u16)(kw.x & 0xFFFF)) * q0.x + bf2f((u16)(kw.x >> 16)) * q0.y;
      dot += bf2f((u16)(kw.y & 0xFFFF)) * q0.z + bf2f((u16)(kw.y >> 16)) * q0.w;
      dot += bf2f((u16)(kw.z & 0xFFFF)) * q1.x + bf2f((u16)(kw.z >> 16)) * q1.y;
      dot += bf2f((u16)(kw.w & 0xFFFF)) * q1.z + bf2f((u16)(kw.w >> 16)) * q1.w;
    }
    float g0 = bg2_s[h * 3 + 0], g1v = bg2_s[h * 3 + 1], g2v = bg2_s[h * 3 + 2];
#pragma unroll
    for (int i = 0; i < 24; i++) {
      float pr = pre_s[n][i];
      int b = i * 24 + h * 3;
      g0  += pr * wg2_s[b + 0];
      g1v += pr * wg2_s[b + 1];
      g2v += pr * wg2_s[b + 2];
    }
    float pos = g0 * sh_s[n][0] + g1v * sh_s[n][1] + g2v * sh_s[n][2];
    float rw = raw[(size_t)p * 256 + t];
    logit_s[n][h] = __expf((dot + pos + rw) * 0.17677669529663687f);
  }
  __syncthreads();

  if (t < 64) {  // partial sums: h = t&7, group g = t>>3 covers n = 4g..4g+3
    int h = t & 7, g = t >> 3;
    float s = logit_s[g * 4 + 0][h] + logit_s[g * 4 + 1][h]
            + logit_s[g * 4 + 2][h] + logit_s[g * 4 + 3][h];
    ps_s[h * 8 + g] = s;
  }
  __syncthreads();
  if (t < 8) {
    float s = 0.f;
#pragma unroll
    for (int g = 0; g < 8; g++) s += ps_s[t * 8 + g];
    is_s[t] = 1.f / s;
  }
  __syncthreads();

  {  // write att[p][h][n]
    int h = t >> 5, n = t & 31;
    att[(size_t)p * 256 + t] = logit_s[n][h] * is_s[h];
  }
}

// ---------------------------------------------------------------------------
// Kernel 3: PV. 4 points/block, 1 wave/point, 4 cols/lane.
// Touches only vbuf (gather) -> 4MB working set, L2-resident.
// ---------------------------------------------------------------------------
__global__ __launch_bounds__(256) void attn_pv(
    const u16* __restrict__ vb, const float* __restrict__ att,
    const int* __restrict__ ip, float* __restrict__ out)
{
  int p0 = blockIdx.x * 4, t = threadIdx.x;
  int wid = t >> 6, l = t & 63;
  int p = p0 + wid;
  __shared__ __align__(16) float att_s[4][256];
  __shared__            int   idx_s[4][32];

  *(float4*)&att_s[wid][l * 4] = *(const float4*)(att + (size_t)p * 256 + l * 4);
  if (l < 32) idx_s[wid][l] = ip[(size_t)p * 32 + l];
  __syncthreads();

  int h = l >> 3;  // (l*4)>>5
  float a0 = 0.f, a1 = 0.f, a2 = 0.f, a3 = 0.f;
#pragma unroll
  for (int n = 0; n < 32; n++) {
    float w = att_s[wid][h * 32 + n];
    const uint2 vv = *(const uint2*)(vb + (size_t)idx_s[wid][n] * 256 + l * 4);
    a0 += w * bf2f((u16)(vv.x & 0xFFFF));
    a1 += w * bf2f((u16)(vv.x >> 16));
    a2 += w * bf2f((u16)(vv.y & 0xFFFF));
    a3 += w * bf2f((u16)(vv.y >> 16));
  }
  float4 r; r.x = a0; r.y = a1; r.z = a2; r.w = a3;
  *(float4*)(out + (size_t)p * 256 + l * 4) = r;
}

// ---------------------------------------------------------------------------
extern "C" void kernel_launch(void* const* d_in, const int* in_sizes, int n_in,
                              void* d_out, int out_size, void* d_ws, size_t ws_size,
                              hipStream_t stream) {
  const float* query = (const float*)d_in[0];
  const float* key_x = (const float*)d_in[1];
  const float* value = (const float*)d_in[2];
  const int*   index_pair = (const int*)d_in[3];
  const float* raw  = (const float*)d_in[4];
  const float* rpe  = (const float*)d_in[5];
  const float* Wq = (const float*)d_in[6];
  const float* bq = (const float*)d_in[7];
  const float* Wk = (const float*)d_in[8];
  const float* bk = (const float*)d_in[9];
  const float* Wv = (const float*)d_in[10];
  const float* bv = (const float*)d_in[11];
  const float* Wg1 = (const float*)d_in[12];
  const float* bg1 = (const float*)d_in[13];
  const float* Wg2 = (const float*)d_in[14];
  const float* bg2 = (const float*)d_in[15];
  float* out = (float*)d_out;

  char* ws = (char*)d_ws;
  u16*   qbuf = (u16*)(ws);                            // 4MB  [8192][256] bf16
  u16*   kbuf = (u16*)(ws + (4u << 20));               // 4MB
  u16*   vbuf = (u16*)(ws + (8u << 20));               // 4MB
  float* att  = (float*)(ws + (12u << 20));            // 8MB  [8192][8][32] f32
  float* qadj = (float*)(ws + (20u << 20));            // 768KB [8192][24] f32
  float* kg1  = (float*)(ws + (20u << 20) + 786432);   // 768KB
  u16*   WTq  = (u16*)(ws + (20u << 20) + 2 * 786432); // 128KB each
  u16*   WTk  = WTq + 65536;
  u16*   WTv  = WTk + 65536;
  u16*   CT   = WTv + 65536;                           // 2 x [32][256] bf16
  float* bcomb = (float*)(CT + 16384);                 // 48 f32

  prep_transpose<<<dim3(8, 8, 3), dim3(32, 8, 1), 0, stream>>>(
      Wq, Wk, Wv, WTq, WTk, WTv);
  prep_comb<<<dim3(24, 2), 256, 0, stream>>>(
      WTq, WTk, Wg1, bg1, bq, bk, CT, bcomb);
  gemm_qkv<<<dim3(3, 64, 3), 256, 0, stream>>>(
      query, key_x, value, WTq, WTk, WTv, bq, bk, bv, CT, bcomb,
      qbuf, kbuf, vbuf, qadj, kg1);
  attn_logits<<<8192, 256, 0, stream>>>(
      qbuf, kbuf, kg1, qadj, index_pair, raw, rpe, Wg2, bg2, att);
  attn_pv<<<2048, 256, 0, stream>>>(
      vbuf, att, index_pair, out);
}

// Round 4
// 75.688 us; speedup vs baseline: 1.0454x; 1.0454x over previous
//
#include <hip/hip_runtime.h>
#include <stdint.h>

typedef uint32_t u32;
typedef unsigned short u16;

#define LDT 40  // padded LDS row stride (elements) -> 80B rows, 16B-aligned

typedef __bf16 bf16x8 __attribute__((ext_vector_type(8)));
typedef float  f32x4  __attribute__((ext_vector_type(4)));

__device__ __forceinline__ float bf2f(u16 x) {
  union { float f; u32 u; } c; c.u = ((u32)x) << 16; return c.f;
}
__device__ __forceinline__ u16 f2bf(float f) {
  union { float f; u32 u; } c; c.f = f;
  u32 b = c.u;
  return (u16)((b + 0x7FFFu + ((b >> 16) & 1u)) >> 16);
}
__device__ __forceinline__ u32 pk2(float lo, float hi) {
  return (u32)f2bf(lo) | ((u32)f2bf(hi) << 16);
}

// ---------------------------------------------------------------------------
// Kernel 0: transpose+cast Wq/Wk/Wv (f32 [256][256] -> bf16 WT [n][k])
// ---------------------------------------------------------------------------
__global__ __launch_bounds__(256) void prep_transpose(
    const float* __restrict__ Wq, const float* __restrict__ Wk, const float* __restrict__ Wv,
    u16* __restrict__ WTq, u16* __restrict__ WTk, u16* __restrict__ WTv)
{
  int z = blockIdx.z, bx = blockIdx.x, by = blockIdx.y;
  int x = threadIdx.x, y = threadIdx.y;  // 32 x 8
  __shared__ u16 tile[32][33];
  const float* W  = (z == 0) ? Wq : (z == 1) ? Wk : Wv;
  u16*         WT = (z == 0) ? WTq : (z == 1) ? WTk : WTv;
  for (int yy = y; yy < 32; yy += 8)
    tile[yy][x] = f2bf(W[(size_t)(by * 32 + yy) * 256 + bx * 32 + x]);
  __syncthreads();
  for (int yy = y; yy < 32; yy += 8)
    WT[(size_t)(bx * 32 + yy) * 256 + by * 32 + x] = tile[x][yy];
}

// ---------------------------------------------------------------------------
// Kernel 0b: combined weights CT[z][c][k] = (W{q,k} @ Wg1)^T  (bf16, c<24),
//            bcomb[z][c] = b{q,k}@Wg1 (+ -bg1 for z=0)
// ---------------------------------------------------------------------------
__global__ __launch_bounds__(256) void prep_comb(
    const u16* __restrict__ WTq, const u16* __restrict__ WTk,
    const float* __restrict__ Wg1, const float* __restrict__ bg1,
    const float* __restrict__ bq, const float* __restrict__ bk,
    u16* __restrict__ CT, float* __restrict__ bcomb)
{
  int c = blockIdx.x, z = blockIdx.y;
  int t = threadIdx.x;
  const u16*   WT = (z == 0) ? WTq : WTk;
  const float* b  = (z == 0) ? bq : bk;

  float acc = 0.f;
#pragma unroll 8
  for (int e = 0; e < 256; e++)
    acc += bf2f(WT[(size_t)e * 256 + t]) * Wg1[(size_t)e * 24 + c];
  CT[(size_t)z * 8192 + (size_t)c * 256 + t] = f2bf(acc);

  __shared__ float red[256];
  red[t] = b[t] * Wg1[(size_t)t * 24 + c];
  __syncthreads();
  for (int s = 128; s > 0; s >>= 1) {
    if (t < s) red[t] += red[t + s];
    __syncthreads();
  }
  if (t == 0)
    bcomb[z * 24 + c] = red[0] - ((z == 0) ? bg1[c] : 0.f);
}

// ---------------------------------------------------------------------------
// Kernel 1: projections. blockIdx.x<2: Y[8192,256]=X@W+b (bf16 out).
// blockIdx.x==2: extra 24 cols via combined weights -> qadj/kg1 (f32 out).
// ---------------------------------------------------------------------------
__global__ __launch_bounds__(256) void gemm_qkv(
    const float* __restrict__ Xq, const float* __restrict__ Xk, const float* __restrict__ Xv,
    const u16* __restrict__ WTq, const u16* __restrict__ WTk, const u16* __restrict__ WTv,
    const float* __restrict__ bq, const float* __restrict__ bk, const float* __restrict__ bv,
    const u16* __restrict__ CT, const float* __restrict__ bcomb,
    u16* __restrict__ Oq, u16* __restrict__ Ok, u16* __restrict__ Ov,
    float* __restrict__ qadj, float* __restrict__ kg1)
{
  int z = blockIdx.z;
  int nblk = blockIdx.x;
  if (nblk == 2 && z == 2) return;

  const float* X = (z == 0) ? Xq : (z == 1) ? Xk : Xv;
  int m0 = blockIdx.y * 128;
  int t = threadIdx.x;
  int lane = t & 63, wid = t >> 6;
  int fr = lane & 15, fg = lane >> 4;
  int sr = t >> 1;
  int sc = (t & 1) * 16;

  __shared__ __align__(16) u16 la[128 * LDT];
  __shared__ __align__(16) u16 lb[128 * LDT];

  if (nblk < 2) {
    const u16*   WT   = (z == 0) ? WTq : (z == 1) ? WTk : WTv;
    const float* bias = (z == 0) ? bq : (z == 1) ? bk : bv;
    u16*         O    = (z == 0) ? Oq : (z == 1) ? Ok : Ov;
    int n0 = nblk * 128;
    int wr = wid >> 1, wc = wid & 1;

    f32x4 acc[4][4];
#pragma unroll
    for (int i = 0; i < 4; i++)
#pragma unroll
      for (int j = 0; j < 4; j++) acc[i][j] = (f32x4){0.f, 0.f, 0.f, 0.f};

    for (int kt = 0; kt < 256; kt += 32) {
      const float4* ga = (const float4*)(X + (size_t)(m0 + sr) * 256 + kt + sc);
      float4 a0 = ga[0], a1 = ga[1], a2 = ga[2], a3 = ga[3];
      const uint4* gb = (const uint4*)(WT + (size_t)(n0 + sr) * 256 + kt + sc);
      uint4 b0 = gb[0], b1 = gb[1];

      uint4 wa0, wa1;
      wa0.x = pk2(a0.x, a0.y); wa0.y = pk2(a0.z, a0.w);
      wa0.z = pk2(a1.x, a1.y); wa0.w = pk2(a1.z, a1.w);
      wa1.x = pk2(a2.x, a2.y); wa1.y = pk2(a2.z, a2.w);
      wa1.z = pk2(a3.x, a3.y); wa1.w = pk2(a3.z, a3.w);

      __syncthreads();
      *(uint4*)&la[sr * LDT + sc]     = wa0;
      *(uint4*)&la[sr * LDT + sc + 8] = wa1;
      *(uint4*)&lb[sr * LDT + sc]     = b0;
      *(uint4*)&lb[sr * LDT + sc + 8] = b1;
      __syncthreads();

      bf16x8 af[4], bfr[4];
#pragma unroll
      for (int s = 0; s < 4; s++)
        af[s] = *(const bf16x8*)&la[(wr * 64 + s * 16 + fr) * LDT + fg * 8];
#pragma unroll
      for (int s = 0; s < 4; s++)
        bfr[s] = *(const bf16x8*)&lb[(wc * 64 + s * 16 + fr) * LDT + fg * 8];
#pragma unroll
      for (int i = 0; i < 4; i++)
#pragma unroll
        for (int j = 0; j < 4; j++)
          acc[i][j] = __builtin_amdgcn_mfma_f32_16x16x32_bf16(af[i], bfr[j], acc[i][j], 0, 0, 0);
    }

#pragma unroll
    for (int i = 0; i < 4; i++) {
      int rowb = m0 + wr * 64 + i * 16 + fg * 4;
#pragma unroll
      for (int j = 0; j < 4; j++) {
        int col = n0 + wc * 64 + j * 16 + fr;
        float bb = bias[col];
#pragma unroll
        for (int r = 0; r < 4; r++)
          O[(size_t)(rowb + r) * 256 + col] = f2bf(acc[i][j][r] + bb);
      }
    }
  } else {
    const u16*   BT = CT + (size_t)z * 8192;
    const float* bc = bcomb + z * 24;
    float*       O  = (z == 0) ? qadj : kg1;

    f32x4 acc[2][2];
#pragma unroll
    for (int i = 0; i < 2; i++)
#pragma unroll
      for (int j = 0; j < 2; j++) acc[i][j] = (f32x4){0.f, 0.f, 0.f, 0.f};

    for (int kt = 0; kt < 256; kt += 32) {
      const float4* ga = (const float4*)(X + (size_t)(m0 + sr) * 256 + kt + sc);
      float4 a0 = ga[0], a1 = ga[1], a2 = ga[2], a3 = ga[3];
      uint4 b0, b1;
      if (t < 64) {
        const uint4* gb = (const uint4*)(BT + (size_t)sr * 256 + kt + sc);
        b0 = gb[0]; b1 = gb[1];
      }
      uint4 wa0, wa1;
      wa0.x = pk2(a0.x, a0.y); wa0.y = pk2(a0.z, a0.w);
      wa0.z = pk2(a1.x, a1.y); wa0.w = pk2(a1.z, a1.w);
      wa1.x = pk2(a2.x, a2.y); wa1.y = pk2(a2.z, a2.w);
      wa1.z = pk2(a3.x, a3.y); wa1.w = pk2(a3.z, a3.w);

      __syncthreads();
      *(uint4*)&la[sr * LDT + sc]     = wa0;
      *(uint4*)&la[sr * LDT + sc + 8] = wa1;
      if (t < 64) {
        *(uint4*)&lb[sr * LDT + sc]     = b0;
        *(uint4*)&lb[sr * LDT + sc + 8] = b1;
      }
      __syncthreads();

      bf16x8 af[2], bfr[2];
#pragma unroll
      for (int s = 0; s < 2; s++)
        af[s] = *(const bf16x8*)&la[(wid * 32 + s * 16 + fr) * LDT + fg * 8];
#pragma unroll
      for (int s = 0; s < 2; s++)
        bfr[s] = *(const bf16x8*)&lb[(s * 16 + fr) * LDT + fg * 8];
#pragma unroll
      for (int i = 0; i < 2; i++)
#pragma unroll
        for (int j = 0; j < 2; j++)
          acc[i][j] = __builtin_amdgcn_mfma_f32_16x16x32_bf16(af[i], bfr[j], acc[i][j], 0, 0, 0);
    }

#pragma unroll
    for (int i = 0; i < 2; i++) {
      int rowb = m0 + wid * 32 + i * 16 + fg * 4;
#pragma unroll
      for (int j = 0; j < 2; j++) {
        int col = j * 16 + fr;
        if (col < 24) {
#pragma unroll
          for (int r = 0; r < 4; r++)
            O[(size_t)(rowb + r) * 24 + col] = acc[i][j][r] + bc[col];
        }
      }
    }
  }
}

// ---------------------------------------------------------------------------
// Kernel 2: fused edge/attention. One 256-thread block (4 waves) per point.
// MLP layer-2 done with 4x mfma_f32_16x16x32_bf16 (one per wave).
// ---------------------------------------------------------------------------
__global__ __launch_bounds__(256) void edge_attn(
    const u16* __restrict__ qb, const u16* __restrict__ kb, const u16* __restrict__ vb,
    const float* __restrict__ kg1, const float* __restrict__ qadj,
    const int* __restrict__ ip, const float* __restrict__ raw,
    const float* __restrict__ rpe, const float* __restrict__ wg2g,
    const float* __restrict__ bg2g, float* __restrict__ out)
{
  int p = blockIdx.x, t = threadIdx.x;
  int lane = t & 63, w = t >> 6;

  __shared__ __align__(16) float q_s[256];
  __shared__              int   idx_s[32];
  __shared__              float rpe_s[96];
  __shared__              float sh_s[32][3];
  __shared__              float qadj_s[24];
  __shared__              float bg2_s[24];
  __shared__ __align__(16) u16  wg2T[32 * 40];   // [col j][k i] bf16, zero-padded
  __shared__ __align__(16) u16  preb[32 * 40];   // [edge n][k i] bf16, cols 24..31 = 0
  __shared__ __align__(16) float kg1_s[32 * 24];
  __shared__              float g_s[32 * 33];    // [edge][col], stride 33
  __shared__              float logit_s[32][8];
  __shared__              float ps_s[64];
  __shared__              float is_s[8];
  __shared__ __align__(16) float pv_s[4 * 256];

  // ---- Phase A: stage everything that has no intra-block dependency
  q_s[t] = bf2f(qb[(size_t)p * 256 + t]);
  if (t < 32) idx_s[t] = ip[(size_t)p * 32 + t];
  if (t < 96) rpe_s[t] = rpe[(size_t)p * 96 + t];
  if (t >= 128 && t < 152) qadj_s[t - 128] = qadj[(size_t)p * 24 + (t - 128)];
  if (t >= 160 && t < 184) bg2_s[t - 160] = bg2g[t - 160];
  {
    // fill Wg2^T (j<24, i<24) from global; zero the padded region. Disjoint slots.
    int s0 = 2 * t, s1 = 2 * t + 1;
    { int i = s0 / 24, j = s0 - i * 24; if (s0 < 576) wg2T[j * 40 + i] = f2bf(wg2g[s0]); }
    { int i = s1 / 24, j = s1 - i * 24; if (s1 < 576) wg2T[j * 40 + i] = f2bf(wg2g[s1]); }
    if (t < 64) { int s = 512 + t; int i = s / 24, j = s - i * 24; wg2T[j * 40 + i] = f2bf(wg2g[s]); }
    wg2T[(t >> 3) * 40 + 24 + (t & 7)] = 0;                      // i in 24..31, all j
    if (t < 192) wg2T[(24 + t / 24) * 40 + (t % 24)] = 0;        // j in 24..31, i<24
  }
  __syncthreads();

  // ---- Phase B: gathered kg1 rows + spherical harmonics
  if (t < 192) {
    int n = t / 6, f = t % 6;
    *(float4*)&kg1_s[n * 24 + f * 4] = ((const float4*)(kg1 + (size_t)idx_s[n] * 24))[f];
  }
  if (t < 32) {
    float x  = rpe_s[t * 3 + 0];
    float y  = rpe_s[t * 3 + 1];
    float zz = rpe_s[t * 3 + 2];
    float rl = sqrtf(x * x + y * y + zz * zz);
    float inv = 1.f / fmaxf(rl, 1e-12f);
    float tt = (rl - 0.001f) * 250.f;
    tt = fminf(fmaxf(tt, 0.f), 1.f);
    float cut = 0.5f * (1.f - cosf(tt * 3.14159265358979f));
    float s3c = 1.7320508075688772f * inv * cut;
    sh_s[t][0] = x * s3c; sh_s[t][1] = y * s3c; sh_s[t][2] = zz * s3c;
  }
  __syncthreads();

  // ---- Phase C: pre = relu(kg1_g - qadj) -> bf16 [32 edges][32 k] (cols >=24 zero)
  {
    int n = t >> 3, jj = t & 7;
    float v0, v1, v2, v3;
    int j0 = jj * 4;
    v0 = (j0 + 0 < 24) ? fmaxf(kg1_s[n * 24 + j0 + 0] - qadj_s[j0 + 0], 0.f) : 0.f;
    v1 = (j0 + 1 < 24) ? fmaxf(kg1_s[n * 24 + j0 + 1] - qadj_s[j0 + 1], 0.f) : 0.f;
    v2 = (j0 + 2 < 24) ? fmaxf(kg1_s[n * 24 + j0 + 2] - qadj_s[j0 + 2], 0.f) : 0.f;
    v3 = (j0 + 3 < 24) ? fmaxf(kg1_s[n * 24 + j0 + 3] - qadj_s[j0 + 3], 0.f) : 0.f;
    uint2 pw; pw.x = pk2(v0, v1); pw.y = pk2(v2, v3);
    *(uint2*)&preb[n * 40 + j0] = pw;
  }
  __syncthreads();

  // ---- Phase D: g = pre @ Wg2 + bg2 via one MFMA per wave
  {
    int mt = w & 1, nt = w >> 1;
    int fr = lane & 15, fg = lane >> 4;
    bf16x8 a = *(const bf16x8*)&preb[(mt * 16 + fr) * 40 + fg * 8];
    bf16x8 b = *(const bf16x8*)&wg2T[(nt * 16 + fr) * 40 + fg * 8];
    f32x4 acc = (f32x4){0.f, 0.f, 0.f, 0.f};
    acc = __builtin_amdgcn_mfma_f32_16x16x32_bf16(a, b, acc, 0, 0, 0);
    int j = nt * 16 + fr;
    float bb = (j < 24) ? bg2_s[j] : 0.f;
    int e0 = mt * 16 + fg * 4;
#pragma unroll
    for (int r = 0; r < 4; r++)
      g_s[(e0 + r) * 33 + j] = acc[r] + bb;
  }
  __syncthreads();

  // ---- Phase E: logits + exp (max-free; |logit| <~ 12, f32-safe)
  {
    int n = t >> 3, h = t & 7;
    const uint4*  kr = (const uint4*)(kb + (size_t)idx_s[n] * 256 + h * 32);
    const float4* qr = (const float4*)(q_s + h * 32);
    float dot = 0.f;
#pragma unroll
    for (int c = 0; c < 4; c++) {
      uint4 kw = kr[c];
      float4 q0 = qr[2 * c], q1 = qr[2 * c + 1];
      dot += bf2f((u16)(kw.x & 0xFFFF)) * q0.x + bf2f((u16)(kw.x >> 16)) * q0.y;
      dot += bf2f((u16)(kw.y & 0xFFFF)) * q0.z + bf2f((u16)(kw.y >> 16)) * q0.w;
      dot += bf2f((u16)(kw.z & 0xFFFF)) * q1.x + bf2f((u16)(kw.z >> 16)) * q1.y;
      dot += bf2f((u16)(kw.w & 0xFFFF)) * q1.z + bf2f((u16)(kw.w >> 16)) * q1.w;
    }
    float pos = g_s[n * 33 + h * 3 + 0] * sh_s[n][0]
              + g_s[n * 33 + h * 3 + 1] * sh_s[n][1]
              + g_s[n * 33 + h * 3 + 2] * sh_s[n][2];
    float rw = raw[(size_t)p * 256 + t];
    logit_s[n][h] = __expf((dot + pos + rw) * 0.17677669529663687f);
  }
  __syncthreads();

  // ---- Phase F: softmax denominators (parallel partial sums)
  if (t < 64) {
    int h = t & 7, g = t >> 3;
    ps_s[h * 8 + g] = logit_s[g * 4 + 0][h] + logit_s[g * 4 + 1][h]
                    + logit_s[g * 4 + 2][h] + logit_s[g * 4 + 3][h];
  }
  __syncthreads();
  if (t < 8) {
    float s = 0.f;
#pragma unroll
    for (int g = 0; g < 8; g++) s += ps_s[t * 8 + g];
    is_s[t] = 1.f / s;
  }
  __syncthreads();

  // ---- Phase G: PV. wave w sums n in [8w, 8w+8); lane covers 4 cols.
  {
    int c0 = lane * 4;
    int hh = lane >> 3;           // head of cols c0..c0+3
    float isv = is_s[hh];
    float a0 = 0.f, a1 = 0.f, a2 = 0.f, a3 = 0.f;
#pragma unroll
    for (int i = 0; i < 8; i++) {
      int n = w * 8 + i;
      float wt = logit_s[n][hh] * isv;
      uint2 vv = *(const uint2*)(vb + (size_t)idx_s[n] * 256 + c0);
      a0 += wt * bf2f((u16)(vv.x & 0xFFFF));
      a1 += wt * bf2f((u16)(vv.x >> 16));
      a2 += wt * bf2f((u16)(vv.y & 0xFFFF));
      a3 += wt * bf2f((u16)(vv.y >> 16));
    }
    float4 r; r.x = a0; r.y = a1; r.z = a2; r.w = a3;
    *(float4*)&pv_s[w * 256 + c0] = r;
  }
  __syncthreads();

  out[(size_t)p * 256 + t] = pv_s[t] + pv_s[256 + t] + pv_s[512 + t] + pv_s[768 + t];
}

// ---------------------------------------------------------------------------
extern "C" void kernel_launch(void* const* d_in, const int* in_sizes, int n_in,
                              void* d_out, int out_size, void* d_ws, size_t ws_size,
                              hipStream_t stream) {
  const float* query = (const float*)d_in[0];
  const float* key_x = (const float*)d_in[1];
  const float* value = (const float*)d_in[2];
  const int*   index_pair = (const int*)d_in[3];
  const float* raw  = (const float*)d_in[4];
  const float* rpe  = (const float*)d_in[5];
  const float* Wq = (const float*)d_in[6];
  const float* bq = (const float*)d_in[7];
  const float* Wk = (const float*)d_in[8];
  const float* bk = (const float*)d_in[9];
  const float* Wv = (const float*)d_in[10];
  const float* bv = (const float*)d_in[11];
  const float* Wg1 = (const float*)d_in[12];
  const float* bg1 = (const float*)d_in[13];
  const float* Wg2 = (const float*)d_in[14];
  const float* bg2 = (const float*)d_in[15];
  float* out = (float*)d_out;

  char* ws = (char*)d_ws;
  u16*   qbuf = (u16*)(ws);                            // 4MB  [8192][256] bf16
  u16*   kbuf = (u16*)(ws + (4u << 20));               // 4MB
  u16*   vbuf = (u16*)(ws + (8u << 20));               // 4MB
  float* qadj = (float*)(ws + (12u << 20));            // 768KB [8192][24] f32
  float* kg1  = (float*)(ws + (12u << 20) + 786432);   // 768KB
  u16*   WTq  = (u16*)(ws + (12u << 20) + 2 * 786432); // 128KB each
  u16*   WTk  = WTq + 65536;
  u16*   WTv  = WTk + 65536;
  u16*   CT   = WTv + 65536;                           // 2 x [32][256] bf16
  float* bcomb = (float*)(CT + 16384);                 // 48 f32

  prep_transpose<<<dim3(8, 8, 3), dim3(32, 8, 1), 0, stream>>>(
      Wq, Wk, Wv, WTq, WTk, WTv);
  prep_comb<<<dim3(24, 2), 256, 0, stream>>>(
      WTq, WTk, Wg1, bg1, bq, bk, CT, bcomb);
  gemm_qkv<<<dim3(3, 64, 3), 256, 0, stream>>>(
      query, key_x, value, WTq, WTk, WTv, bq, bk, bv, CT, bcomb,
      qbuf, kbuf, vbuf, qadj, kg1);
  edge_attn<<<8192, 256, 0, stream>>>(
      qbuf, kbuf, vbuf, kg1, qadj, index_pair, raw, rpe, Wg2, bg2, out);
}